// Round 3
// baseline (89.862 us; speedup 1.0000x reference)
//
#include <hip/hip_runtime.h>
#include <hip/hip_bf16.h>

// ContrastiveLoss: loss = ( sum_{same & sim<1} (1-sim) + sum_{diff & sim>0.5} sim ) / n
// sim = E E^T, n=8192, d=512. bf16 MFMA GEMM fused with mask/sum epilogue.
// R3: m201-geometry port — 256x256 tile, BK=64, 8 waves (2x4), 128KB dbuf LDS,
// T2 XOR-swizzle (inverse-swizzled global source + swizzled ds_read),
// per-tile single early vmcnt(0) + issue-early staging, 4 quadrant phases with
// setprio(1) MFMA clusters. Triangular grid, epilogue weight (i<j)?2:0.

typedef __bf16 bf16x8 __attribute__((ext_vector_type(8)));
typedef __bf16 bf16x4 __attribute__((ext_vector_type(4)));
typedef float  f32x4  __attribute__((ext_vector_type(4)));

#define N_EMB 8192
#define D_EMB 512
#define BM    256            // tile rows == tile cols
#define BK    64
#define KT    (D_EMB / BK)   // 8 K-tiles
#define TILES (N_EMB / BM)   // 32
#define NBLK  (TILES * (TILES + 1) / 2)   // 528
#define MARGIN_F 0.5f
#define TILE_ELEMS (BM * BK) // 16384 elements per operand tile

__device__ __forceinline__ void gll16(const __bf16* g, __bf16* l) {
    __builtin_amdgcn_global_load_lds(
        (const __attribute__((address_space(1))) void*)g,
        (__attribute__((address_space(3))) void*)l,
        16 /*bytes*/, 0 /*offset*/, 0 /*aux*/);
}

__global__ __launch_bounds__(256) void cvt_kernel(const float* __restrict__ in,
                                                  __bf16* __restrict__ out, int n4) {
    int i = blockIdx.x * blockDim.x + threadIdx.x;
    if (i < n4) {
        float4 v = reinterpret_cast<const float4*>(in)[i];
        bf16x4 o;
        o.x = (__bf16)v.x; o.y = (__bf16)v.y; o.z = (__bf16)v.z; o.w = (__bf16)v.w;
        reinterpret_cast<bf16x4*>(out)[i] = o;
    }
}

__global__ __launch_bounds__(512, 2) void loss_kernel(const __bf16* __restrict__ E,
                                                      const int* __restrict__ label,
                                                      float* __restrict__ partials) {
    // triangular decode: block t -> (tr, tc), tr <= tc
    const int t = blockIdx.x;
    int tr = (int)((65.0f - sqrtf(4225.0f - 8.0f * (float)t)) * 0.5f);
    if (tr < 0) tr = 0; if (tr > TILES - 1) tr = TILES - 1;
    while ((tr + 1) * TILES - ((tr + 1) * tr) / 2 <= t) ++tr;
    while (tr * TILES - (tr * (tr - 1)) / 2 > t) --tr;
    const int tc = tr + (t - (tr * TILES - (tr * (tr - 1)) / 2));

    // LDS: 2 buffers, each = A tile (256x64) then B tile (256x64), bf16.
    __shared__ __bf16 lds[2][2 * TILE_ELEMS];   // 128 KB
    __shared__ float  red[8];

    const int tid  = threadIdx.x;
    const int wid  = tid >> 6, lane = tid & 63;
    const int wrow = wid >> 2, wcol = wid & 3;   // 2x4 waves; wave out = 128x64
    const int fr   = lane & 15;                  // fragment row(A)/row(B)/col(C)
    const int kq   = lane >> 4;                  // k-quarter 0..3 (8 elems each)
    const int fr7  = fr & 7;

    const int row0 = tr * BM, col0 = tc * BM;

    // ---- staging map (T2 swizzle, rule #21: linear LDS dest, inverse-swizzled
    // global source). Physical 16B slot (srow, s=tid&7) holds logical slot
    // s ^ (srow&7) of row srow. ----
    const int srow  = tid >> 3;              // 0..63 within a 64-row issue chunk
    const int lslot = (tid & 7) ^ (srow & 7);
    const __bf16* sA0 = E + (size_t)(row0 + srow) * D_EMB + lslot * 8;
    const __bf16* sB0 = E + (size_t)(col0 + srow) * D_EMB + lslot * 8;

    f32x4 acc[8][4] = {};

    // prologue: stage K-tile 0 into buf 0 (8 glls; 4 x 64-row chunks per operand)
    {
        __bf16* dA = lds[0];
        __bf16* dB = lds[0] + TILE_ELEMS;
#pragma unroll
        for (int i = 0; i < 4; ++i) {
            gll16(sA0 + (size_t)i * 64 * D_EMB, dA + i * 4096 + tid * 8);
            gll16(sB0 + (size_t)i * 64 * D_EMB, dB + i * 4096 + tid * 8);
        }
    }

#pragma unroll 1
    for (int kt = 0; kt < KT; ++kt) {
        const __bf16* Ab = lds[kt & 1];
        const __bf16* Bb = lds[kt & 1] + TILE_ELEMS;

        // tile barrier: this tile's stages landed (issued >= 4 phases ago),
        // and all waves are done reading the buffer we are about to overwrite.
        asm volatile("s_waitcnt vmcnt(0)" ::: "memory");
        asm volatile("s_barrier" ::: "memory");

        // issue-early: stage K-tile kt+1 into the other buffer
        if (kt + 1 < KT) {
            __bf16* dA = lds[(kt + 1) & 1];
            __bf16* dB = lds[(kt + 1) & 1] + TILE_ELEMS;
            const int k1 = (kt + 1) * BK;
#pragma unroll
            for (int i = 0; i < 4; ++i) {
                gll16(sA0 + (size_t)i * 64 * D_EMB + k1, dA + i * 4096 + tid * 8);
                gll16(sB0 + (size_t)i * 64 * D_EMB + k1, dB + i * 4096 + tid * 8);
            }
        }

        // b-fragments for the whole K-tile (held in regs across all 4 phases)
        bf16x8 b[4][2];
#pragma unroll
        for (int nn = 0; nn < 4; ++nn)
#pragma unroll
            for (int kh = 0; kh < 2; ++kh)
                b[nn][kh] = *reinterpret_cast<const bf16x8*>(
                    &Bb[(wcol * 64 + nn * 16 + fr) * BK + (((kh * 4 + kq) ^ fr7) << 3)]);

        // 4 quadrant phases: phase q computes m in {2q, 2q+1} x all n x K=64
#pragma unroll
        for (int q = 0; q < 4; ++q) {
            bf16x8 a[2][2];
#pragma unroll
            for (int mi = 0; mi < 2; ++mi)
#pragma unroll
                for (int kh = 0; kh < 2; ++kh)
                    a[mi][kh] = *reinterpret_cast<const bf16x8*>(
                        &Ab[(wrow * 128 + (2 * q + mi) * 16 + fr) * BK +
                            (((kh * 4 + kq) ^ fr7) << 3)]);
            asm volatile("s_barrier" ::: "memory");
            __builtin_amdgcn_s_setprio(1);
#pragma unroll
            for (int mi = 0; mi < 2; ++mi)
#pragma unroll
                for (int nn = 0; nn < 4; ++nn) {
                    acc[2 * q + mi][nn] = __builtin_amdgcn_mfma_f32_16x16x32_bf16(
                        a[mi][0], b[nn][0], acc[2 * q + mi][nn], 0, 0, 0);
                    acc[2 * q + mi][nn] = __builtin_amdgcn_mfma_f32_16x16x32_bf16(
                        a[mi][1], b[nn][1], acc[2 * q + mi][nn], 0, 0, 0);
                }
            __builtin_amdgcn_s_setprio(0);
        }
    }

    // ---- epilogue: C/D layout col = lane&15, row = (lane>>4)*4 + reg [m89].
    // weight: 2 if i<j else 0 (diagonal self-pairs contribute 0 in ref anyway).
    float local = 0.f;
    int lj[4];
#pragma unroll
    for (int nn = 0; nn < 4; ++nn) lj[nn] = label[col0 + wcol * 64 + nn * 16 + fr];
    const int rb = kq << 2;
#pragma unroll
    for (int mm = 0; mm < 8; ++mm) {
#pragma unroll
        for (int rr = 0; rr < 4; ++rr) {
            const int gi = row0 + wrow * 128 + mm * 16 + rb + rr;
            const int li = label[gi];
#pragma unroll
            for (int nn = 0; nn < 4; ++nn) {
                const int gj = col0 + wcol * 64 + nn * 16 + fr;
                const float s = acc[mm][nn][rr];
                float term = 0.f;
                if (li == lj[nn]) {
                    if (s < 1.0f) term = 1.0f - s;
                } else if (s > MARGIN_F) {
                    term = s;
                }
                local += (gi < gj) ? 2.0f * term : 0.f;
            }
        }
    }

#pragma unroll
    for (int off = 32; off > 0; off >>= 1) local += __shfl_xor(local, off);
    if (lane == 0) red[wid] = local;
    __syncthreads();
    if (tid == 0) {
        float s = 0.f;
#pragma unroll
        for (int i = 0; i < 8; ++i) s += red[i];
        partials[t] = s;
    }
}

__global__ __launch_bounds__(256) void reduce_kernel(const float* __restrict__ partials,
                                                     float* __restrict__ out, int nb) {
    float s = 0.f;
    for (int i = threadIdx.x; i < nb; i += 256) s += partials[i];
#pragma unroll
    for (int off = 32; off > 0; off >>= 1) s += __shfl_xor(s, off);
    __shared__ float red[4];
    if ((threadIdx.x & 63) == 0) red[threadIdx.x >> 6] = s;
    __syncthreads();
    if (threadIdx.x == 0) {
        out[0] = (red[0] + red[1] + red[2] + red[3]) * (1.0f / (float)N_EMB);
        out[1] = 0.f;
        out[2] = 0.f;
    }
}

extern "C" void kernel_launch(void* const* d_in, const int* in_sizes, int n_in,
                              void* d_out, int out_size, void* d_ws, size_t ws_size,
                              hipStream_t stream) {
    const float* emb   = (const float*)d_in[0];
    const int*   label = (const int*)d_in[1];
    float*       out   = (float*)d_out;

    __bf16* Ebf     = (__bf16*)d_ws;                                     // 8 MB
    float*  partial = (float*)((char*)d_ws + (size_t)N_EMB * D_EMB * 2); // 2.1 KB

    const int n4 = N_EMB * D_EMB / 4;
    cvt_kernel<<<(n4 + 255) / 256, 256, 0, stream>>>(emb, Ebf, n4);

    loss_kernel<<<NBLK, 512, 0, stream>>>(Ebf, label, partial);

    reduce_kernel<<<1, 256, 0, stream>>>(partial, out, NBLK);
}

// Round 4
// 65.950 us; speedup vs baseline: 1.3626x; 1.3626x over previous
//
#include <hip/hip_runtime.h>
#include <hip/hip_bf16.h>

// ContrastiveLoss: loss = ( sum_{same & sim<1} (1-sim) + sum_{diff & sim>0.5} sim ) / n
// sim = E E^T, n=8192, d=512. bf16 MFMA GEMM fused with mask/sum epilogue.
// R4: back to the R2 128^2 / 8-wave geometry (3 blocks/CU), plus
//  - T4 counted vmcnt: 3-buffer LDS, 2-deep prefetch, vmcnt(2) in main loop
//    (never 0), ONE barrier per K-iter.
//  - T2 XOR swizzle (slot ^= row&3): inverse-swizzled global source, linear
//    gll dest, swizzled ds_read -> 2 lanes/bank (free).
//  - T1 XCD-aware block swizzle (2080 = 8*260 exactly).

typedef __bf16 bf16x8 __attribute__((ext_vector_type(8)));
typedef __bf16 bf16x4 __attribute__((ext_vector_type(4)));
typedef float  f32x4  __attribute__((ext_vector_type(4)));

#define N_EMB 8192
#define D_EMB 512
#define BM    128
#define BK    32
#define KT    (D_EMB / BK)      // 16
#define TILES (N_EMB / BM)      // 64
#define NBLK  (TILES * (TILES + 1) / 2)   // 2080
#define MARGIN_F 0.5f
#define OPER  (BM * BK)         // 4096 elems per operand tile

__device__ __forceinline__ void gll16(const __bf16* g, __bf16* l) {
    __builtin_amdgcn_global_load_lds(
        (const __attribute__((address_space(1))) void*)g,
        (__attribute__((address_space(3))) void*)l,
        16 /*bytes*/, 0 /*offset*/, 0 /*aux*/);
}

__global__ __launch_bounds__(256) void cvt_kernel(const float* __restrict__ in,
                                                  __bf16* __restrict__ out, int n4) {
    int i = blockIdx.x * blockDim.x + threadIdx.x;
    if (i < n4) {
        float4 v = reinterpret_cast<const float4*>(in)[i];
        bf16x4 o;
        o.x = (__bf16)v.x; o.y = (__bf16)v.y; o.z = (__bf16)v.z; o.w = (__bf16)v.w;
        reinterpret_cast<bf16x4*>(out)[i] = o;
    }
}

__global__ __launch_bounds__(512, 6) void loss_kernel(const __bf16* __restrict__ E,
                                                      const int* __restrict__ label,
                                                      float* __restrict__ partials) {
    // T1: XCD-contiguous logical tile index (2080 % 8 == 0)
    const int bid = blockIdx.x;
    const int t = (bid & 7) * (NBLK / 8) + (bid >> 3);

    // triangular decode: t -> (tr, tc), tr <= tc (verified in R2)
    int tr = (int)(64.5f - sqrtf(4160.25f - 2.0f * (float)t));
    while ((tr + 1) * TILES - ((tr + 1) * tr) / 2 <= t) ++tr;
    while (tr * TILES - (tr * (tr - 1)) / 2 > t) --tr;
    const int tc = tr + (t - (tr * TILES - (tr * (tr - 1)) / 2));

    __shared__ __bf16 lds[3][2 * OPER];   // 3 x 16 KB (A tile then B tile)
    __shared__ float  red[8];

    const int tid  = threadIdx.x;
    const int wid  = tid >> 6, lane = tid & 63;
    const int wrow = wid >> 2, wcol = wid & 3;   // 2x4 waves, each 64x32 out
    const int fr   = lane & 15;                  // fragment row(A)/row(B)/col(C)
    const int kq   = lane >> 4;                  // logical k-octet 0..3
    const int row0 = tr * BM, col0 = tc * BM;

    // ---- staging map: thread -> (row = tid>>2, phys slot s = tid&3).
    // Physical slot s of row holds LOGICAL slot s ^ (row&3)  (T2, rule #21:
    // linear LDS dest, inverse-swizzled global source).
    const int srow  = tid >> 2;
    const int sslot = ((tid & 3) ^ (srow & 3)) << 3;   // element offset in row
    const __bf16* gA = E + (size_t)(row0 + srow) * D_EMB + sslot;
    const __bf16* gB = E + (size_t)(col0 + srow) * D_EMB + sslot;
    const int dA = tid << 3;          // element offset of this thread's 16B slot
    const int dB = OPER + (tid << 3);

    f32x4 acc[4][2] = {};

    // swizzled ds_read offset within a row: phys slot = kq ^ (row&3); all
    // fragment rows have row&3 == fr&3.
    const int ps = ((kq ^ (fr & 3)) << 3);

    // prologue: stage tiles 0 and 1 (4 glls outstanding)
    {
        __bf16* L0 = lds[0]; __bf16* L1 = lds[1];
        gll16(gA,      L0 + dA); gll16(gB,      L0 + dB);
        gll16(gA + BK, L1 + dA); gll16(gB + BK, L1 + dB);
    }

    __bf16* rd  = lds[0];   // tile kt lives here
    __bf16* pre = lds[1];   // tile kt+1
    __bf16* wr  = lds[2];   // tile kt+2 staged into here

#pragma unroll 1
    for (int kt = 0; kt < KT - 1; ++kt) {
        // wait: tile kt's 2 glls done (tile kt+1's 2 still in flight)
        asm volatile("s_waitcnt vmcnt(2)" ::: "memory");
        __builtin_amdgcn_s_barrier();   // kt's data visible; buf 'wr' free (read at kt-1)

        if (kt + 2 < KT) {
            const int k2 = (kt + 2) * BK;
            gll16(gA + k2, wr + dA);
            gll16(gB + k2, wr + dB);
        }
        __builtin_amdgcn_sched_barrier(0);   // keep stage-issue ahead of compute

        bf16x8 a[4], b[2];
#pragma unroll
        for (int m = 0; m < 4; ++m)
            a[m] = *reinterpret_cast<const bf16x8*>(&rd[(wrow * 64 + m * 16 + fr) * BK + ps]);
#pragma unroll
        for (int n = 0; n < 2; ++n)
            b[n] = *reinterpret_cast<const bf16x8*>(&rd[OPER + (wcol * 32 + n * 16 + fr) * BK + ps]);
#pragma unroll
        for (int m = 0; m < 4; ++m)
#pragma unroll
            for (int n = 0; n < 2; ++n)
                acc[m][n] = __builtin_amdgcn_mfma_f32_16x16x32_bf16(a[m], b[n], acc[m][n], 0, 0, 0);

        __bf16* tmp = rd; rd = pre; pre = wr; wr = tmp;   // rotate
    }

    // last tile: drain everything
    asm volatile("s_waitcnt vmcnt(0)" ::: "memory");
    __builtin_amdgcn_s_barrier();
    {
        bf16x8 a[4], b[2];
#pragma unroll
        for (int m = 0; m < 4; ++m)
            a[m] = *reinterpret_cast<const bf16x8*>(&rd[(wrow * 64 + m * 16 + fr) * BK + ps]);
#pragma unroll
        for (int n = 0; n < 2; ++n)
            b[n] = *reinterpret_cast<const bf16x8*>(&rd[OPER + (wcol * 32 + n * 16 + fr) * BK + ps]);
#pragma unroll
        for (int m = 0; m < 4; ++m)
#pragma unroll
            for (int n = 0; n < 2; ++n)
                acc[m][n] = __builtin_amdgcn_mfma_f32_16x16x32_bf16(a[m], b[n], acc[m][n], 0, 0, 0);
    }

    // ---- epilogue: C/D layout col = lane&15, row = (lane>>4)*4 + reg [m89]
    float local = 0.f;
    int lj[2];
#pragma unroll
    for (int n = 0; n < 2; ++n) lj[n] = label[col0 + wcol * 32 + n * 16 + fr];
    const int rb = kq << 2;
#pragma unroll
    for (int m = 0; m < 4; ++m) {
#pragma unroll
        for (int r = 0; r < 4; ++r) {
            const int li = label[row0 + wrow * 64 + m * 16 + rb + r];
#pragma unroll
            for (int n = 0; n < 2; ++n) {
                const float s = acc[m][n][r];
                if (li == lj[n]) {
                    if (s < 1.0f) local += 1.0f - s;
                } else if (s > MARGIN_F) {
                    local += s;
                }
            }
        }
    }
    if (tr != tc) local *= 2.0f;   // off-diag tile stands for (i,j) and (j,i)

#pragma unroll
    for (int off = 32; off > 0; off >>= 1) local += __shfl_xor(local, off);
    if (lane == 0) red[wid] = local;
    __syncthreads();
    if (tid == 0) {
        float s = 0.f;
#pragma unroll
        for (int i = 0; i < 8; ++i) s += red[i];
        partials[t] = s;
    }
}

__global__ __launch_bounds__(256) void reduce_kernel(const float* __restrict__ partials,
                                                     float* __restrict__ out, int nb) {
    float s = 0.f;
    for (int i = threadIdx.x; i < nb; i += 256) s += partials[i];
#pragma unroll
    for (int off = 32; off > 0; off >>= 1) s += __shfl_xor(s, off);
    __shared__ float red[4];
    if ((threadIdx.x & 63) == 0) red[threadIdx.x >> 6] = s;
    __syncthreads();
    if (threadIdx.x == 0) {
        out[0] = (red[0] + red[1] + red[2] + red[3]) * (1.0f / (float)N_EMB);
        out[1] = 0.f;
        out[2] = 0.f;
    }
}

extern "C" void kernel_launch(void* const* d_in, const int* in_sizes, int n_in,
                              void* d_out, int out_size, void* d_ws, size_t ws_size,
                              hipStream_t stream) {
    const float* emb   = (const float*)d_in[0];
    const int*   label = (const int*)d_in[1];
    float*       out   = (float*)d_out;

    __bf16* Ebf     = (__bf16*)d_ws;                                     // 8 MB
    float*  partial = (float*)((char*)d_ws + (size_t)N_EMB * D_EMB * 2); // 8.3 KB

    const int n4 = N_EMB * D_EMB / 4;
    cvt_kernel<<<(n4 + 255) / 256, 256, 0, stream>>>(emb, Ebf, n4);

    loss_kernel<<<NBLK, 512, 0, stream>>>(Ebf, label, partial);

    reduce_kernel<<<1, 256, 0, stream>>>(partial, out, NBLK);
}